// Round 13
// baseline (223.196 us; speedup 1.0000x reference)
//
#include <hip/hip_runtime.h>
#include <hip/hip_bf16.h>

// SCNN round 13:
//  - k_gemm: wave tile 64x128 (R2xC4, 16 ds_read_b128 : 32 MFMA = 0.5 ratio;
//    r12's 0.75 ratio made LDS the hard cap at ~22% MfmaUtil).
//    BM=128 BN=256 BK=32, 4 waves (2x2), double-buffered 64KB LDS ->
//    2 blocks/CU (2 waves/SIMD), counted vmcnt(8), 384 uniform 16-iter blocks
//    (chunk 512: sk {4,8,4}), mt-pairs same-XCD for B-chunk L2 reuse.
//  - pf packed per-branch split-K: [4sl x2048][8sl x4096][4sl x2048] = 48MB;
//    Y aliases X (dead after gemm) -> ws ~112MB.
//  - k_pre / MLP unchanged.

#define B_    32
#define S_    8
#define BS_   256
#define F_    4
#define IN_   8192
#define H_    1024
#define OUT_  256

#define L_TOT  25165824LL     // 2048^2 + 4096^2 + 2048^2
#define LOFF1  4194304LL
#define LOFF2  20971520LL

// packed pf float offsets
#define PF_B1  2097152LL      // 4*256*2048
#define PF_B2  10485760LL     // PF_B1 + 8*256*4096
#define PF_TOT 12582912LL     // 48MB

typedef __attribute__((ext_vector_type(8)))  short bf16x8;
typedef __attribute__((ext_vector_type(4)))  short short4v;
typedef __attribute__((ext_vector_type(8)))  short short8v;
typedef __attribute__((ext_vector_type(16))) float f32x16;
typedef __attribute__((ext_vector_type(4)))  float f32x4;

typedef const __attribute__((address_space(1))) void* gas_ptr;
typedef __attribute__((address_space(3))) void* las_ptr;

__device__ __forceinline__ void gload16(const void* g, void* s) {
    __builtin_amdgcn_global_load_lds((gas_ptr)g, (las_ptr)s, 16, 0, 0);
}

__device__ __forceinline__ unsigned short rne_bf16(float f) {
    unsigned int u = __builtin_bit_cast(unsigned int, f);
    u += 0x7FFFu + ((u >> 16) & 1u);
    return (unsigned short)(u >> 16);
}

// ---------------- fused prep: L->bf16, x->hi/lo, P/M ----------------
__global__ void k_pre(const float* __restrict__ L0, const float* __restrict__ L1,
                      const float* __restrict__ L2, unsigned short* __restrict__ Lb,
                      const float* __restrict__ x0, const float* __restrict__ x1,
                      const float* __restrict__ x2,
                      unsigned short* __restrict__ Xhi, unsigned short* __restrict__ Xlo,
                      const float* __restrict__ Wc0, const float* __restrict__ Wc1,
                      const float* __restrict__ Wc2, float* __restrict__ PM)
{
    const int bx = blockIdx.x, tid = threadIdx.x;
    if (bx < 3072) {
        const long long b0 = (long long)bx * 8192;   // block-uniform branch
        const float* src; long long off;
        if (b0 < LOFF1)      { src = L0; off = 0; }
        else if (b0 < LOFF2) { src = L1; off = LOFF1; }
        else                 { src = L2; off = LOFF2; }
        const float* pb = src + (b0 - off) + tid * 8;
        #pragma unroll
        for (int u = 0; u < 4; ++u) {
            const float* p = pb + u * 2048;
            f32x4 a = __builtin_nontemporal_load((const f32x4*)p);
            f32x4 b = __builtin_nontemporal_load((const f32x4*)p + 1);
            short8v o;
            o[0] = (short)rne_bf16(a.x); o[1] = (short)rne_bf16(a.y);
            o[2] = (short)rne_bf16(a.z); o[3] = (short)rne_bf16(a.w);
            o[4] = (short)rne_bf16(b.x); o[5] = (short)rne_bf16(b.y);
            o[6] = (short)rne_bf16(b.z); o[7] = (short)rne_bf16(b.w);
            *(short8v*)(Lb + b0 + u * 2048 + tid * 8) = o;
        }
    } else if (bx < 3584) {
        const int base = (bx - 3072) * 4096 + tid * 8;
        #pragma unroll
        for (int u = 0; u < 2; ++u) {
            int e = base + u * 2048;
            int m = e >> 13, c = e & 8191;
            const float* src; int n, c0;
            if (c < 2048)      { src = x0; n = 2048; c0 = c; }
            else if (c < 6144) { src = x1; n = 4096; c0 = c - 2048; }
            else               { src = x2; n = 2048; c0 = c - 6144; }
            const float* p = src + (size_t)m * n + c0;
            f32x4 a = __builtin_nontemporal_load((const f32x4*)p);
            f32x4 b = __builtin_nontemporal_load((const f32x4*)p + 1);
            float v[8] = {a.x, a.y, a.z, a.w, b.x, b.y, b.z, b.w};
            short8v h, l;
            #pragma unroll
            for (int i = 0; i < 8; ++i) {
                unsigned short hb = rne_bf16(v[i]);
                float hf = __builtin_bit_cast(float, (unsigned int)hb << 16);
                h[i] = (short)hb;
                l[i] = (short)rne_bf16(v[i] - hf);
            }
            *(short8v*)(Xhi + (size_t)m * IN_ + c) = h;
            *(short8v*)(Xlo + (size_t)m * IN_ + c) = l;
        }
    } else {
        const int base = (bx - 3584) * 2048 + tid * 8;
        #pragma unroll
        for (int i = 0; i < 8; ++i) {
            int idx = base + i;
            int l = idx / IN_, n = idx % IN_;
            const float* Wc; int nb, j;
            if (n < 2048)      { Wc = Wc0; nb = 2048; j = n;        }
            else if (n < 6144) { Wc = Wc1; nb = 4096; j = n - 2048; }
            else               { Wc = Wc2; nb = 2048; j = n - 6144; }
            float p = 0.f, m = 0.f;
            #pragma unroll
            for (int f = 0; f < F_; ++f) {
                float w = Wc[(l * F_ + f) * nb + j];
                p += fmaxf(w, 0.f);
                m += fmaxf(-w, 0.f);
            }
            PM[(l * 2 + 0) * IN_ + n] = p;
            PM[(l * 2 + 1) * IN_ + n] = m;
        }
    }
}

// ---------------- MFMA GEMM: BM=128 BN=256, wave 64x128, dbuf-2 ----------------
// Grid 384, uniform 16 iters (chunk 512): bx<256 b1 (sk8); 256-319 b0 (sk4);
// 320-383 b2 (sk4). Decode puts mt-pairs of one (nt,sk) on the same XCD.
__global__ __launch_bounds__(256, 2) void k_gemm(
    const unsigned short* __restrict__ Xhi, const unsigned short* __restrict__ Xlo,
    const unsigned short* __restrict__ Lb,
    float* __restrict__ pf)                    // packed [4|8|4]-slot regions
{
    __shared__ __attribute__((aligned(16))) unsigned short Ah[2][128 * 32];  // 8KB/buf
    __shared__ __attribute__((aligned(16))) unsigned short Al[2][128 * 32];
    __shared__ __attribute__((aligned(16))) unsigned short Bs[2][256 * 32];  // 16KB/buf

    const int bx = blockIdx.x;
    int n_, noff, mt, nt, sk, ld; long long loff; size_t pbase;
    if (bx < 256) {                      // branch 1
        int u = bx;
        int j = (u & 7) | ((u >> 4) << 3);      // [0,128)
        nt = j >> 3; sk = j & 7; mt = (u >> 3) & 1;
        n_ = 4096; noff = 2048; loff = LOFF1; pbase = PF_B1; ld = 4096;
    } else if (bx < 320) {               // branch 0
        int u = bx - 256;
        int j = (u & 7) | ((u >> 4) << 3);      // [0,32)
        nt = j >> 2; sk = j & 3; mt = (u >> 3) & 1;
        n_ = 2048; noff = 0; loff = 0; pbase = 0; ld = 2048;
    } else {                             // branch 2
        int u = bx - 320;
        int j = (u & 7) | ((u >> 4) << 3);
        nt = j >> 2; sk = j & 3; mt = (u >> 3) & 1;
        n_ = 2048; noff = 6144; loff = LOFF2; pbase = PF_B2; ld = 2048;
    }
    const int k0 = sk * 512;             // uniform chunk 512 = 16 iters of 32

    const int tid = threadIdx.x;

    // ----- staging sources (pre-swizzled col: (t&3)^((t>>3)&3)) -----
    const int sg = ((tid & 3) ^ ((tid >> 3) & 3)) << 3;
    const unsigned short* gAh = Xhi + (size_t)(mt * 128 + (tid >> 2)) * IN_ + noff + k0 + sg;
    const unsigned short* gAl = Xlo + (size_t)(mt * 128 + (tid >> 2)) * IN_ + noff + k0 + sg;
    const unsigned short* gB  = Lb + loff + (size_t)(nt * 256 + (tid >> 2)) * n_ + k0 + sg;
    const size_t a64 = (size_t)64 * IN_, b64 = (size_t)64 * n_;
    const int tb = tid * 16;

    #define STAGE(buf, ko)                                                      \
        do {                                                                    \
            char* pa = (char*)&Ah[buf][0];                                      \
            char* pl = (char*)&Al[buf][0];                                      \
            char* pb = (char*)&Bs[buf][0];                                      \
            gload16(gAh + (ko),       pa + tb);                                 \
            gload16(gAh + (ko) + a64, pa + 4096 + tb);                          \
            gload16(gAl + (ko),       pl + tb);                                 \
            gload16(gAl + (ko) + a64, pl + 4096 + tb);                          \
            gload16(gB + (ko),           pb + tb);                              \
            gload16(gB + (ko) + b64,     pb + 4096 + tb);                       \
            gload16(gB + (ko) + 2 * b64, pb + 8192 + tb);                       \
            gload16(gB + (ko) + 3 * b64, pb + 12288 + tb);                      \
        } while (0)

    // ----- compute-side addressing: waves 2x2; wave tile 64x128 -----
    const int l = tid & 63, w = tid >> 6;
    const int l31 = l & 31, lh = l >> 5;
    const int wm = w >> 1, wn = w & 1;
    const int swz = (l31 >> 1) & 3;

    f32x16 acc[2][4];
    #pragma unroll
    for (int r = 0; r < 2; ++r)
        #pragma unroll
        for (int c = 0; c < 4; ++c)
            #pragma unroll
            for (int e = 0; e < 16; ++e) acc[r][c][e] = 0.f;

    STAGE(0, 0);
    STAGE(1, 32);

    for (int it = 0; it < 16; ++it) {
        if (it < 15) asm volatile("s_waitcnt vmcnt(8)" ::: "memory");
        else         asm volatile("s_waitcnt vmcnt(0)" ::: "memory");
        __builtin_amdgcn_s_barrier();
        asm volatile("" ::: "memory");

        const int cur = it & 1;
        const unsigned short* cA = &Ah[cur][0];
        const unsigned short* cL = &Al[cur][0];
        const unsigned short* cB = &Bs[cur][0];
        __builtin_amdgcn_s_setprio(1);
        #pragma unroll
        for (int t = 0; t < 2; ++t) {
            const int sidx = (((t << 1) + lh) ^ swz) << 3;
            bf16x8 fah[2], fal[2], fb[4];
            #pragma unroll
            for (int r = 0; r < 2; ++r) {
                fah[r] = *(const bf16x8*)&cA[(wm * 64 + r * 32 + l31) * 32 + sidx];
                fal[r] = *(const bf16x8*)&cL[(wm * 64 + r * 32 + l31) * 32 + sidx];
            }
            #pragma unroll
            for (int c = 0; c < 4; ++c)
                fb[c] = *(const bf16x8*)&cB[(wn * 128 + c * 32 + l31) * 32 + sidx];
            #pragma unroll
            for (int r = 0; r < 2; ++r)
                #pragma unroll
                for (int c = 0; c < 4; ++c) {
                    acc[r][c] = __builtin_amdgcn_mfma_f32_32x32x16_bf16(fal[r], fb[c], acc[r][c], 0, 0, 0);
                    acc[r][c] = __builtin_amdgcn_mfma_f32_32x32x16_bf16(fah[r], fb[c], acc[r][c], 0, 0, 0);
                }
        }
        __builtin_amdgcn_s_setprio(0);
        asm volatile("" ::: "memory");
        __builtin_amdgcn_s_barrier();            // all waves done reading buf[cur]

        if (it + 2 < 16) STAGE(cur, (it + 2) * 32);   // refill just-consumed buffer
        asm volatile("" ::: "memory");
    }
    #undef STAGE

    // ----- partial store into packed pf region -----
    const int colL = nt * 256 + wn * 128 + l31;       // branch-local col base
    float* pw = pf + pbase + (size_t)sk * 256 * ld;
    #pragma unroll
    for (int r = 0; r < 2; ++r) {
        const int rowb = mt * 128 + wm * 64 + r * 32 + 4 * lh;
        #pragma unroll
        for (int e = 0; e < 16; ++e) {
            const int row = rowb + (e & 3) + 8 * (e >> 2);
            #pragma unroll
            for (int c = 0; c < 4; ++c)
                pw[(size_t)row * ld + colL + c * 32] = acc[r][c][e];
        }
    }
}

// ---------------- branch decode for packed pf ----------------
__device__ __forceinline__ void pf_decode(int c, size_t& base, int& nsl, int& ld, int& cl) {
    if (c < 2048)      { base = 0;      nsl = 4; ld = 2048; cl = c; }
    else if (c < 6144) { base = PF_B1;  nsl = 8; ld = 4096; cl = c - 2048; }
    else               { base = PF_B2;  nsl = 4; ld = 2048; cl = c - 6144; }
}

// ---------------- epi0: slot-sum + relu*P/M + hi/lo re-split ----------------
__global__ void k_epi0(const float* __restrict__ pf,
                       const float* __restrict__ Pv, const float* __restrict__ Mv,
                       unsigned short* __restrict__ Yhi, unsigned short* __restrict__ Ylo) {
    int e = (blockIdx.x * 256 + threadIdx.x) * 4;   // over [256][8192]
    int m = e >> 13, c = e & 8191;
    size_t base; int nsl, ld, cl;
    pf_decode(c, base, nsl, ld, cl);
    const float* p0 = pf + base + (size_t)m * ld + cl;
    const size_t sstr = (size_t)256 * ld;
    float vs[4] = {0.f, 0.f, 0.f, 0.f};
    for (int s = 0; s < nsl; ++s) {
        float4 v = *(const float4*)(p0 + (size_t)s * sstr);
        vs[0] += v.x; vs[1] += v.y; vs[2] += v.z; vs[3] += v.w;
    }
    float4 pv = *(const float4*)(Pv + c);
    float4 mv = *(const float4*)(Mv + c);
    float pa[4] = {pv.x, pv.y, pv.z, pv.w};
    float ma[4] = {mv.x, mv.y, mv.z, mv.w};
    short hv[4], lv[4];
    #pragma unroll
    for (int j = 0; j < 4; ++j) {
        float y = fmaxf(vs[j], 0.f) * pa[j] + fmaxf(-vs[j], 0.f) * ma[j];
        unsigned short hb = rne_bf16(y);
        float hf = __builtin_bit_cast(float, (unsigned int)hb << 16);
        hv[j] = (short)hb;
        lv[j] = (short)rne_bf16(y - hf);
    }
    short4v h = {hv[0], hv[1], hv[2], hv[3]};
    short4v lo = {lv[0], lv[1], lv[2], lv[3]};
    *(short4v*)(Yhi + (size_t)m * IN_ + c) = h;
    *(short4v*)(Ylo + (size_t)m * IN_ + c) = lo;
}

// ---------------- epi1s: slot-sum + relu*P/M + sum over S -> hsum ----------------
__global__ void k_epi1s(const float* __restrict__ pf,
                        const float* __restrict__ Pv, const float* __restrict__ Mv,
                        float* __restrict__ hsum) {
    int e = (blockIdx.x * 256 + threadIdx.x) * 4;   // over [32][8192]
    int b = e >> 13, c = e & 8191;
    size_t base; int nsl, ld, cl;
    pf_decode(c, base, nsl, ld, cl);
    const size_t sstr = (size_t)256 * ld;
    float4 pv = *(const float4*)(Pv + c);
    float4 mv = *(const float4*)(Mv + c);
    float pa[4] = {pv.x, pv.y, pv.z, pv.w};
    float ma[4] = {mv.x, mv.y, mv.z, mv.w};
    float hs[4] = {0.f, 0.f, 0.f, 0.f};
    for (int q = 0; q < 8; ++q) {
        const int m = b * 8 + q;
        const float* p0 = pf + base + (size_t)m * ld + cl;
        float vs[4] = {0.f, 0.f, 0.f, 0.f};
        for (int s = 0; s < nsl; ++s) {
            float4 v = *(const float4*)(p0 + (size_t)s * sstr);
            vs[0] += v.x; vs[1] += v.y; vs[2] += v.z; vs[3] += v.w;
        }
        #pragma unroll
        for (int j = 0; j < 4; ++j)
            hs[j] += fmaxf(vs[j], 0.f) * pa[j] + fmaxf(-vs[j], 0.f) * ma[j];
    }
    *(float4*)(hsum + (size_t)b * IN_ + c) = *(float4*)hs;
}

// ---------------- MLP split-K partial GEMM (BW-shaped) ----------------
template<int KC>
__global__ __launch_bounds__(256) void k_mlp3(
    const float* __restrict__ X, const float* __restrict__ W,
    float* __restrict__ P, int K, int H)
{
    __shared__ float Xs[32][KC];
    const int tid = threadIdx.x;
    const int lane = tid & 63;
    const int mg = tid >> 6;
    const int h = (blockIdx.x * 64 + lane) * 4;
    const int c = blockIdx.y, k0 = c * KC;

    for (int i = tid * 4; i < 32 * KC; i += 1024) {
        int m = i / KC, kk = i % KC;
        *(float4*)&Xs[m][kk] = *(const float4*)(X + (size_t)m * K + k0 + kk);
    }
    __syncthreads();

    float4 acc[8];
    #pragma unroll
    for (int m = 0; m < 8; ++m) acc[m] = {0.f, 0.f, 0.f, 0.f};

    const float* wp = W + (size_t)k0 * H + h;
    for (int kk = 0; kk < KC; kk += 4) {
        float4 w4[4];
        #pragma unroll
        for (int u = 0; u < 4; ++u)
            w4[u] = *(const float4*)(wp + (size_t)(kk + u) * H);
        #pragma unroll
        for (int m = 0; m < 8; ++m) {
            float4 xv = *(const float4*)&Xs[mg * 8 + m][kk];
            acc[m].x = fmaf(xv.x, w4[0].x, acc[m].x);
            acc[m].y = fmaf(xv.x, w4[0].y, acc[m].y);
            acc[m].z = fmaf(xv.x, w4[0].z, acc[m].z);
            acc[m].w = fmaf(xv.x, w4[0].w, acc[m].w);
            acc[m].x = fmaf(xv.y, w4[1].x, acc[m].x);
            acc[m].y = fmaf(xv.y, w4[1].y, acc[m].y);
            acc[m].z = fmaf(xv.y, w4[1].z, acc[m].z);
            acc[m].w = fmaf(xv.y, w4[1].w, acc[m].w);
            acc[m].x = fmaf(xv.z, w4[2].x, acc[m].x);
            acc[m].y = fmaf(xv.z, w4[2].y, acc[m].y);
            acc[m].z = fmaf(xv.z, w4[2].z, acc[m].z);
            acc[m].w = fmaf(xv.z, w4[2].w, acc[m].w);
            acc[m].x = fmaf(xv.w, w4[3].x, acc[m].x);
            acc[m].y = fmaf(xv.w, w4[3].y, acc[m].y);
            acc[m].z = fmaf(xv.w, w4[3].z, acc[m].z);
            acc[m].w = fmaf(xv.w, w4[3].w, acc[m].w);
        }
    }
    #pragma unroll
    for (int m = 0; m < 8; ++m)
        *(float4*)(P + ((size_t)c * 32 + mg * 8 + m) * H + h) = acc[m];
}

// ---------------- reduce partials + bias (+relu), float4 ----------------
__global__ void k_reduce4(const float* __restrict__ P, const float* __restrict__ bias,
                          float* __restrict__ Y, int NC, int MH4, int H, int do_relu) {
    int idx = blockIdx.x * 256 + threadIdx.x;
    if (idx >= MH4) return;
    int h0 = (idx * 4) % H;
    float4 s = *(const float4*)(bias + h0);
    for (int c = 0; c < NC; ++c) {
        float4 v = *(const float4*)(P + (size_t)c * MH4 * 4 + (size_t)idx * 4);
        s.x += v.x; s.y += v.y; s.z += v.z; s.w += v.w;
    }
    if (do_relu) {
        s.x = fmaxf(s.x, 0.f); s.y = fmaxf(s.y, 0.f);
        s.z = fmaxf(s.z, 0.f); s.w = fmaxf(s.w, 0.f);
    }
    *(float4*)(Y + (size_t)idx * 4) = s;
}

extern "C" void kernel_launch(void* const* d_in, const int* in_sizes, int n_in,
                              void* d_out, int out_size, void* d_ws, size_t ws_size,
                              hipStream_t stream) {
    const float* xs0  = (const float*)d_in[0];
    const float* xs1  = (const float*)d_in[1];
    const float* xs2  = (const float*)d_in[2];
    const float* L0   = (const float*)d_in[3];
    const float* L1   = (const float*)d_in[4];
    const float* L2   = (const float*)d_in[5];
    const float* Wc0  = (const float*)d_in[6];
    const float* Wc1  = (const float*)d_in[7];
    const float* Wc2  = (const float*)d_in[8];
    const float* W_in = (const float*)d_in[9];
    const float* b_in = (const float*)d_in[10];
    const float* W_h  = (const float*)d_in[11];
    const float* b_h  = (const float*)d_in[12];
    const float* W_out= (const float*)d_in[13];
    const float* b_out= (const float*)d_in[14];

    char* w = (char*)d_ws;
    float*          PM  = (float*)w;          w += (size_t)4 * IN_ * 4;          // 128 KB
    unsigned short* Lb  = (unsigned short*)w; w += (size_t)L_TOT * 2;            // 50.3 MB
    unsigned short* Xhi = (unsigned short*)w; w += (size_t)BS_ * IN_ * 2;        // 4 MB
    unsigned short* Xlo = (unsigned short*)w; w += (size_t)BS_ * IN_ * 2;        // 4 MB
    float*          pf  = (float*)w;          w += (size_t)PF_TOT * 4;           // 48 MB
    float*          hsum= (float*)w;          w += (size_t)32 * IN_ * 4;         // 1 MB
    float*          p1  = pf;                 // alias: pf free after k_epi1s
    float*          h1  = (float*)w;          w += (size_t)32 * H_ * 4;
    float*          p2  = (float*)w;          w += (size_t)32 * 32 * H_ * 4;     // 4 MB
    float*          h2  = (float*)w;          w += (size_t)32 * H_ * 4;
    float*          p3  = (float*)w;          w += (size_t)32 * 32 * OUT_ * 4;   // 1 MB
    // Y aliases X: Xhi/Xlo are dead once gemm1 finishes (stream-ordered)
    unsigned short* Yhi = Xhi;
    unsigned short* Ylo = Xlo;
    // total ~112.5 MB

    k_pre<<<3592, 256, 0, stream>>>(L0, L1, L2, Lb, xs0, xs1, xs2, Xhi, Xlo,
                                    Wc0, Wc1, Wc2, PM);

    k_gemm<<<384, 256, 0, stream>>>(Xhi, Xlo, Lb, pf);
    k_epi0<<<2048, 256, 0, stream>>>(pf, PM + 0 * IN_, PM + 1 * IN_, Yhi, Ylo);
    k_gemm<<<384, 256, 0, stream>>>(Yhi, Ylo, Lb, pf);
    k_epi1s<<<256, 256, 0, stream>>>(pf, PM + 2 * IN_, PM + 3 * IN_, hsum);

    {   // [32,8192]@[8192,1024]: grid (4 h-tiles, 128 k-chunks of 64)
        dim3 g(4, 128);
        k_mlp3<64><<<g, 256, 0, stream>>>(hsum, W_in, p1, IN_, H_);
        k_reduce4<<<32, 256, 0, stream>>>(p1, b_in, h1, 128, 8192, H_, 1);
    }
    {   // [32,1024]@[1024,1024]: grid (4, 32 chunks of 32)
        dim3 g(4, 32);
        k_mlp3<32><<<g, 256, 0, stream>>>(h1, W_h, p2, H_, H_);
        k_reduce4<<<32, 256, 0, stream>>>(p2, b_h, h2, 32, 8192, H_, 1);
    }
    {   // [32,1024]@[1024,256]: grid (1, 32 chunks of 32)
        dim3 g(1, 32);
        k_mlp3<32><<<g, 256, 0, stream>>>(h2, W_out, p3, H_, OUT_);
        k_reduce4<<<8, 256, 0, stream>>>(p3, b_out, (float*)d_out, 32, 2048, OUT_, 0);
    }
}

// Round 14
// 203.607 us; speedup vs baseline: 1.0962x; 1.0962x over previous
//
#include <hip/hip_runtime.h>
#include <hip/hip_bf16.h>

// SCNN round 14: 8-phase-style gemm (T3+T4+T5 per guide §5.5).
//  - k_gemm: BM=128(fused hi/lo) BN=256 BK=64, 512 thr / 8 waves (2x4),
//    wave 64x64. LDS = 4 half-K slots x 32KB (Ah|Al|B) = 128KB ring.
//    Per phase: read next-phase frags | 2 gload_lds | 8 MFMA (setprio) |
//    1 barrier. vmcnt(6) once per half (tail 4->0). 192 uniform blocks
//    (chunk 1024: sk {2,4,2}), 16 K64-tiles each.
//  - pf packed {2,4,2}-slot regions (24MB); epi0/epi1s updated.
//  - k_pre / MLP unchanged from round 12.

#define B_    32
#define S_    8
#define BS_   256
#define F_    4
#define IN_   8192
#define H_    1024
#define OUT_  256

#define L_TOT  25165824LL
#define LOFF1  4194304LL
#define LOFF2  20971520LL

// packed pf float offsets (fused M=256 rows)
#define PF_B1  1048576LL      // 2*256*2048
#define PF_B2  5242880LL      // PF_B1 + 4*256*4096
#define PF_TOT 6291456LL      // 24MB

typedef __attribute__((ext_vector_type(8)))  short bf16x8;
typedef __attribute__((ext_vector_type(4)))  short short4v;
typedef __attribute__((ext_vector_type(8)))  short short8v;
typedef __attribute__((ext_vector_type(16))) float f32x16;
typedef __attribute__((ext_vector_type(4)))  float f32x4;

typedef const __attribute__((address_space(1))) void* gas_ptr;
typedef __attribute__((address_space(3))) void* las_ptr;

__device__ __forceinline__ void gload16(const void* g, void* s) {
    __builtin_amdgcn_global_load_lds((gas_ptr)g, (las_ptr)s, 16, 0, 0);
}

__device__ __forceinline__ unsigned short rne_bf16(float f) {
    unsigned int u = __builtin_bit_cast(unsigned int, f);
    u += 0x7FFFu + ((u >> 16) & 1u);
    return (unsigned short)(u >> 16);
}

// ---------------- fused prep: L->bf16, x->hi/lo, P/M ----------------
__global__ void k_pre(const float* __restrict__ L0, const float* __restrict__ L1,
                      const float* __restrict__ L2, unsigned short* __restrict__ Lb,
                      const float* __restrict__ x0, const float* __restrict__ x1,
                      const float* __restrict__ x2,
                      unsigned short* __restrict__ Xhi, unsigned short* __restrict__ Xlo,
                      const float* __restrict__ Wc0, const float* __restrict__ Wc1,
                      const float* __restrict__ Wc2, float* __restrict__ PM)
{
    const int bx = blockIdx.x, tid = threadIdx.x;
    if (bx < 3072) {
        const long long b0 = (long long)bx * 8192;
        const float* src; long long off;
        if (b0 < LOFF1)      { src = L0; off = 0; }
        else if (b0 < LOFF2) { src = L1; off = LOFF1; }
        else                 { src = L2; off = LOFF2; }
        const float* pb = src + (b0 - off) + tid * 8;
        #pragma unroll
        for (int u = 0; u < 4; ++u) {
            const float* p = pb + u * 2048;
            f32x4 a = __builtin_nontemporal_load((const f32x4*)p);
            f32x4 b = __builtin_nontemporal_load((const f32x4*)p + 1);
            short8v o;
            o[0] = (short)rne_bf16(a.x); o[1] = (short)rne_bf16(a.y);
            o[2] = (short)rne_bf16(a.z); o[3] = (short)rne_bf16(a.w);
            o[4] = (short)rne_bf16(b.x); o[5] = (short)rne_bf16(b.y);
            o[6] = (short)rne_bf16(b.z); o[7] = (short)rne_bf16(b.w);
            *(short8v*)(Lb + b0 + u * 2048 + tid * 8) = o;
        }
    } else if (bx < 3584) {
        const int base = (bx - 3072) * 4096 + tid * 8;
        #pragma unroll
        for (int u = 0; u < 2; ++u) {
            int e = base + u * 2048;
            int m = e >> 13, c = e & 8191;
            const float* src; int n, c0;
            if (c < 2048)      { src = x0; n = 2048; c0 = c; }
            else if (c < 6144) { src = x1; n = 4096; c0 = c - 2048; }
            else               { src = x2; n = 2048; c0 = c - 6144; }
            const float* p = src + (size_t)m * n + c0;
            f32x4 a = __builtin_nontemporal_load((const f32x4*)p);
            f32x4 b = __builtin_nontemporal_load((const f32x4*)p + 1);
            float v[8] = {a.x, a.y, a.z, a.w, b.x, b.y, b.z, b.w};
            short8v h, l;
            #pragma unroll
            for (int i = 0; i < 8; ++i) {
                unsigned short hb = rne_bf16(v[i]);
                float hf = __builtin_bit_cast(float, (unsigned int)hb << 16);
                h[i] = (short)hb;
                l[i] = (short)rne_bf16(v[i] - hf);
            }
            *(short8v*)(Xhi + (size_t)m * IN_ + c) = h;
            *(short8v*)(Xlo + (size_t)m * IN_ + c) = l;
        }
    } else {
        const int base = (bx - 3584) * 2048 + tid * 8;
        #pragma unroll
        for (int i = 0; i < 8; ++i) {
            int idx = base + i;
            int l = idx / IN_, n = idx % IN_;
            const float* Wc; int nb, j;
            if (n < 2048)      { Wc = Wc0; nb = 2048; j = n;        }
            else if (n < 6144) { Wc = Wc1; nb = 4096; j = n - 2048; }
            else               { Wc = Wc2; nb = 2048; j = n - 6144; }
            float p = 0.f, m = 0.f;
            #pragma unroll
            for (int f = 0; f < F_; ++f) {
                float w = Wc[(l * F_ + f) * nb + j];
                p += fmaxf(w, 0.f);
                m += fmaxf(-w, 0.f);
            }
            PM[(l * 2 + 0) * IN_ + n] = p;
            PM[(l * 2 + 1) * IN_ + n] = m;
        }
    }
}

// ---------------- 8-phase MFMA GEMM ----------------
struct Frag6 { bf16x8 ah0, ah1, al0, al1, b0, b1; };

__global__ __launch_bounds__(512, 1) void k_gemm(
    const unsigned short* __restrict__ Xhi, const unsigned short* __restrict__ Xlo,
    const unsigned short* __restrict__ Lb,
    float* __restrict__ pf)
{
    __shared__ __attribute__((aligned(16))) char lds[4 * 32768];   // 128KB, 4 half-slots

    const int bx = blockIdx.x;
    int n_, noff, mt, nt, sk, ld; long long loff; size_t pbase;
    if (bx < 128) {                       // branch 1: 2mt x 16nt x 4sk
        sk = bx & 3; int v = bx >> 2; mt = v & 1; nt = v >> 1;
        n_ = 4096; noff = 2048; loff = LOFF1; pbase = PF_B1; ld = 4096;
    } else if (bx < 160) {                // branch 0: 2mt x 8nt x 2sk
        int u = bx - 128; sk = u & 1; mt = (u >> 1) & 1; nt = u >> 2;
        n_ = 2048; noff = 0; loff = 0; pbase = 0; ld = 2048;
    } else {                              // branch 2
        int u = bx - 160; sk = u & 1; mt = (u >> 1) & 1; nt = u >> 2;
        n_ = 2048; noff = 6144; loff = LOFF2; pbase = PF_B2; ld = 2048;
    }
    const int k0 = sk << 10;              // chunk 1024 = 32 halves of 32 K-cols

    const int tid = threadIdx.x;

    // ----- staging (per half, per thread: 4 x gload16) -----
    // A: 128 rows x 32 K (8KB): row=tid>>2, slot tid&3; source col pre-swizzled
    const int sg = ((tid & 3) ^ ((tid >> 3) & 3)) << 3;   // ushort offset
    const unsigned short* gA = Xhi + (size_t)(mt * 128 + (tid >> 2)) * IN_ + noff + k0 + sg;
    const unsigned short* gL = Xlo + (size_t)(mt * 128 + (tid >> 2)) * IN_ + noff + k0 + sg;
    const unsigned short* gB = Lb + loff + (size_t)(nt * 256 + (tid >> 2)) * n_ + k0 + sg;
    const unsigned short* gB2 = gB + (size_t)128 * n_;
    const int tb = tid * 16;
    char* lb = lds;

    #define ISS_A(u) do { const int _s = (u) & 3; const int _ko = (u) * 32;     \
        gload16(gA + _ko, lb + _s * 32768 + tb);                                \
        gload16(gL + _ko, lb + _s * 32768 + 8192 + tb); } while (0)
    #define ISS_B(u) do { const int _s = (u) & 3; const int _ko = (u) * 32;     \
        gload16(gB + _ko,  lb + _s * 32768 + 16384 + tb);                       \
        gload16(gB2 + _ko, lb + _s * 32768 + 24576 + tb); } while (0)

    // ----- compute-side addressing: 8 waves 2x4, wave tile 64x64 -----
    const int l = tid & 63, w = tid >> 6;
    const int l31 = l & 31, lh = l >> 5;
    const int wm = w >> 2, wn = w & 3;
    const int swz = (l31 >> 1) & 3;
    const int rA0 = (wm * 64 + l31) * 64;        // byte offset within A region
    const int rB0 = (wn * 64 + l31) * 64;        // byte offset within B region

    f32x16 a00, a01, a10, a11;
    #pragma unroll
    for (int r = 0; r < 16; ++r) { a00[r] = 0.f; a01[r] = 0.f; a10[r] = 0.f; a11[r] = 0.f; }

    #define READ6(Fv, s, j) do {                                                \
        const int _se = ((((j) * 2 + lh) ^ swz) << 4);                          \
        const char* _b = lb + (s) * 32768;                                      \
        Fv.ah0 = *(const bf16x8*)(_b + rA0 + _se);                              \
        Fv.ah1 = *(const bf16x8*)(_b + rA0 + 2048 + _se);                       \
        Fv.al0 = *(const bf16x8*)(_b + 8192 + rA0 + _se);                       \
        Fv.al1 = *(const bf16x8*)(_b + 8192 + rA0 + 2048 + _se);                \
        Fv.b0  = *(const bf16x8*)(_b + 16384 + rB0 + _se);                      \
        Fv.b1  = *(const bf16x8*)(_b + 16384 + rB0 + 2048 + _se); } while (0)

    #define MFMA8(Fv) do {                                                      \
        __builtin_amdgcn_s_setprio(1);                                          \
        a00 = __builtin_amdgcn_mfma_f32_32x32x16_bf16(Fv.al0, Fv.b0, a00, 0, 0, 0); \
        a00 = __builtin_amdgcn_mfma_f32_32x32x16_bf16(Fv.ah0, Fv.b0, a00, 0, 0, 0); \
        a01 = __builtin_amdgcn_mfma_f32_32x32x16_bf16(Fv.al0, Fv.b1, a01, 0, 0, 0); \
        a01 = __builtin_amdgcn_mfma_f32_32x32x16_bf16(Fv.ah0, Fv.b1, a01, 0, 0, 0); \
        a10 = __builtin_amdgcn_mfma_f32_32x32x16_bf16(Fv.al1, Fv.b0, a10, 0, 0, 0); \
        a10 = __builtin_amdgcn_mfma_f32_32x32x16_bf16(Fv.ah1, Fv.b0, a10, 0, 0, 0); \
        a11 = __builtin_amdgcn_mfma_f32_32x32x16_bf16(Fv.al1, Fv.b1, a11, 0, 0, 0); \
        a11 = __builtin_amdgcn_mfma_f32_32x32x16_bf16(Fv.ah1, Fv.b1, a11, 0, 0, 0); \
        __builtin_amdgcn_s_setprio(0); } while (0)

    // prologue: 3 halves in flight, sync half 0, read first frags
    ISS_A(0); ISS_B(0);
    ISS_A(1); ISS_B(1);
    ISS_A(2); ISS_B(2);
    asm volatile("s_waitcnt vmcnt(8)" ::: "memory");
    __builtin_amdgcn_s_barrier();
    asm volatile("" ::: "memory");

    Frag6 F0, F1;
    READ6(F0, 0, 0);

    for (int u = 0; u < 32; ++u) {
        const int s = u & 3;
        // ---- phase (u,0): compute F0, read F1 = (u,1), issue A of half u+3
        READ6(F1, s, 1);
        if (u + 3 < 32) ISS_A(u + 3);
        MFMA8(F0);
        if (u <= 28)      asm volatile("s_waitcnt vmcnt(6)" ::: "memory");
        else if (u == 29) asm volatile("s_waitcnt vmcnt(4)" ::: "memory");
        else if (u == 30) asm volatile("s_waitcnt vmcnt(0)" ::: "memory");
        __builtin_amdgcn_s_barrier();
        asm volatile("" ::: "memory");

        // ---- phase (u,1): compute F1, read F0 = (u+1,0), issue B of half u+3
        if (u + 1 < 32) READ6(F0, (u + 1) & 3, 0);
        if (u + 3 < 32) ISS_B(u + 3);
        MFMA8(F1);
        if (u + 1 < 32) {
            __builtin_amdgcn_s_barrier();
            asm volatile("" ::: "memory");
        }
    }
    #undef READ6
    #undef MFMA8
    #undef ISS_A
    #undef ISS_B

    // ----- partial store into packed pf region -----
    const int colb = nt * 256 + wn * 64 + l31;
    float* pw = pf + pbase + (size_t)sk * 256 * ld;
    #pragma unroll
    for (int rb = 0; rb < 2; ++rb) {
        const int rowb = mt * 128 + wm * 64 + rb * 32 + 4 * lh;
        const f32x16& c0 = rb ? a10 : a00;
        const f32x16& c1 = rb ? a11 : a01;
        #pragma unroll
        for (int e = 0; e < 16; ++e) {
            const int row = rowb + (e & 3) + 8 * (e >> 2);
            pw[(size_t)row * ld + colb]      = c0[e];
            pw[(size_t)row * ld + colb + 32] = c1[e];
        }
    }
}

// ---------------- branch decode for packed pf ----------------
__device__ __forceinline__ void pf_decode(int c, size_t& base, int& nsl, int& ld, int& cl) {
    if (c < 2048)      { base = 0;      nsl = 2; ld = 2048; cl = c; }
    else if (c < 6144) { base = PF_B1;  nsl = 4; ld = 4096; cl = c - 2048; }
    else               { base = PF_B2;  nsl = 2; ld = 2048; cl = c - 6144; }
}

// ---------------- epi0: slot-sum + relu*P/M + hi/lo re-split ----------------
__global__ void k_epi0(const float* __restrict__ pf,
                       const float* __restrict__ Pv, const float* __restrict__ Mv,
                       unsigned short* __restrict__ Yhi, unsigned short* __restrict__ Ylo) {
    int e = (blockIdx.x * 256 + threadIdx.x) * 4;   // over [256][8192]
    int m = e >> 13, c = e & 8191;
    size_t base; int nsl, ld, cl;
    pf_decode(c, base, nsl, ld, cl);
    const float* p0 = pf + base + (size_t)m * ld + cl;
    const size_t sstr = (size_t)256 * ld;
    float vs[4] = {0.f, 0.f, 0.f, 0.f};
    for (int s = 0; s < nsl; ++s) {
        float4 v = *(const float4*)(p0 + (size_t)s * sstr);
        vs[0] += v.x; vs[1] += v.y; vs[2] += v.z; vs[3] += v.w;
    }
    float4 pv = *(const float4*)(Pv + c);
    float4 mv = *(const float4*)(Mv + c);
    float pa[4] = {pv.x, pv.y, pv.z, pv.w};
    float ma[4] = {mv.x, mv.y, mv.z, mv.w};
    short hv[4], lv[4];
    #pragma unroll
    for (int j = 0; j < 4; ++j) {
        float y = fmaxf(vs[j], 0.f) * pa[j] + fmaxf(-vs[j], 0.f) * ma[j];
        unsigned short hb = rne_bf16(y);
        float hf = __builtin_bit_cast(float, (unsigned int)hb << 16);
        hv[j] = (short)hb;
        lv[j] = (short)rne_bf16(y - hf);
    }
    short4v h = {hv[0], hv[1], hv[2], hv[3]};
    short4v lo = {lv[0], lv[1], lv[2], lv[3]};
    *(short4v*)(Yhi + (size_t)m * IN_ + c) = h;
    *(short4v*)(Ylo + (size_t)m * IN_ + c) = lo;
}

// ---------------- epi1s: slot-sum + relu*P/M + sum over S -> hsum ----------------
__global__ void k_epi1s(const float* __restrict__ pf,
                        const float* __restrict__ Pv, const float* __restrict__ Mv,
                        float* __restrict__ hsum) {
    int e = (blockIdx.x * 256 + threadIdx.x) * 4;   // over [32][8192]
    int b = e >> 13, c = e & 8191;
    size_t base; int nsl, ld, cl;
    pf_decode(c, base, nsl, ld, cl);
    const size_t sstr = (size_t)256 * ld;
    float4 pv = *(const float4*)(Pv + c);
    float4 mv = *(const float4*)(Mv + c);
    float pa[4] = {pv.x, pv.y, pv.z, pv.w};
    float ma[4] = {mv.x, mv.y, mv.z, mv.w};
    float hs[4] = {0.f, 0.f, 0.f, 0.f};
    for (int q = 0; q < 8; ++q) {
        const int m = b * 8 + q;
        const float* p0 = pf + base + (size_t)m * ld + cl;
        float vs[4] = {0.f, 0.f, 0.f, 0.f};
        for (int s = 0; s < nsl; ++s) {
            float4 v = *(const float4*)(p0 + (size_t)s * sstr);
            vs[0] += v.x; vs[1] += v.y; vs[2] += v.z; vs[3] += v.w;
        }
        #pragma unroll
        for (int j = 0; j < 4; ++j)
            hs[j] += fmaxf(vs[j], 0.f) * pa[j] + fmaxf(-vs[j], 0.f) * ma[j];
    }
    *(float4*)(hsum + (size_t)b * IN_ + c) = *(float4*)hs;
}

// ---------------- MLP split-K partial GEMM (BW-shaped) ----------------
template<int KC>
__global__ __launch_bounds__(256) void k_mlp3(
    const float* __restrict__ X, const float* __restrict__ W,
    float* __restrict__ P, int K, int H)
{
    __shared__ float Xs[32][KC];
    const int tid = threadIdx.x;
    const int lane = tid & 63;
    const int mg = tid >> 6;
    const int h = (blockIdx.x * 64 + lane) * 4;
    const int c = blockIdx.y, k0 = c * KC;

    for (int i = tid * 4; i < 32 * KC; i += 1024) {
        int m = i / KC, kk = i % KC;
        *(float4*)&Xs[m][kk] = *(const float4*)(X + (size_t)m * K + k0 + kk);
    }
    __syncthreads();

    float4 acc[8];
    #pragma unroll
    for (int m = 0; m < 8; ++m) acc[m] = {0.f, 0.f, 0.f, 0.f};

    const float* wp = W + (size_t)k0 * H + h;
    for (int kk = 0; kk < KC; kk += 4) {
        float4 w4[4];
        #pragma unroll
        for (int u = 0; u < 4; ++u)
            w4[u] = *(const float4*)(wp + (size_t)(kk + u) * H);
        #pragma unroll
        for (int m = 0; m < 8; ++m) {
            float4 xv = *(const float4*)&Xs[mg * 8 + m][kk];
            acc[m].x = fmaf(xv.x, w4[0].x, acc[m].x);
            acc[m].y = fmaf(xv.x, w4[0].y, acc[m].y);
            acc[m].z = fmaf(xv.x, w4[0].z, acc[m].z);
            acc[m].w = fmaf(xv.x, w4[0].w, acc[m].w);
            acc[m].x = fmaf(xv.y, w4[1].x, acc[m].x);
            acc[m].y = fmaf(xv.y, w4[1].y, acc[m].y);
            acc[m].z = fmaf(xv.y, w4[1].z, acc[m].z);
            acc[m].w = fmaf(xv.y, w4[1].w, acc[m].w);
            acc[m].x = fmaf(xv.z, w4[2].x, acc[m].x);
            acc[m].y = fmaf(xv.z, w4[2].y, acc[m].y);
            acc[m].z = fmaf(xv.z, w4[2].z, acc[m].z);
            acc[m].w = fmaf(xv.z, w4[2].w, acc[m].w);
            acc[m].x = fmaf(xv.w, w4[3].x, acc[m].x);
            acc[m].y = fmaf(xv.w, w4[3].y, acc[m].y);
            acc[m].z = fmaf(xv.w, w4[3].z, acc[m].z);
            acc[m].w = fmaf(xv.w, w4[3].w, acc[m].w);
        }
    }
    #pragma unroll
    for (int m = 0; m < 8; ++m)
        *(float4*)(P + ((size_t)c * 32 + mg * 8 + m) * H + h) = acc[m];
}

// ---------------- reduce partials + bias (+relu), float4 ----------------
__global__ void k_reduce4(const float* __restrict__ P, const float* __restrict__ bias,
                          float* __restrict__ Y, int NC, int MH4, int H, int do_relu) {
    int idx = blockIdx.x * 256 + threadIdx.x;
    if (idx >= MH4) return;
    int h0 = (idx * 4) % H;
    float4 s = *(const float4*)(bias + h0);
    for (int c = 0; c < NC; ++c) {
        float4 v = *(const float4*)(P + (size_t)c * MH4 * 4 + (size_t)idx * 4);
        s.x += v.x; s.y += v.y; s.z += v.z; s.w += v.w;
    }
    if (do_relu) {
        s.x = fmaxf(s.x, 0.f); s.y = fmaxf(s.y, 0.f);
        s.z = fmaxf(s.z, 0.f); s.w = fmaxf(s.w, 0.f);
    }
    *(float4*)(Y + (size_t)idx * 4) = s;
}

extern "C" void kernel_launch(void* const* d_in, const int* in_sizes, int n_in,
                              void* d_out, int out_size, void* d_ws, size_t ws_size,
                              hipStream_t stream) {
    const float* xs0  = (const float*)d_in[0];
    const float* xs1  = (const float*)d_in[1];
    const float* xs2  = (const float*)d_in[2];
    const float* L0   = (const float*)d_in[3];
    const float* L1   = (const float*)d_in[4];
    const float* L2   = (const float*)d_in[5];
    const float* Wc0  = (const float*)d_in[6];
    const float* Wc1  = (const float*)d_in[7];
    const float* Wc2  = (const float*)d_in[8];
    const float* W_in = (const float*)d_in[9];
    const float* b_in = (const float*)d_in[10];
    const float* W_h  = (const float*)d_in[11];
    const float* b_h  = (const float*)d_in[12];
    const float* W_out= (const float*)d_in[13];
    const float* b_out= (const float*)d_in[14];

    char* w = (char*)d_ws;
    float*          PM  = (float*)w;          w += (size_t)4 * IN_ * 4;          // 128 KB
    unsigned short* Lb  = (unsigned short*)w; w += (size_t)L_TOT * 2;            // 50.3 MB
    unsigned short* Xhi = (unsigned short*)w; w += (size_t)BS_ * IN_ * 2;        // 4 MB
    unsigned short* Xlo = (unsigned short*)w; w += (size_t)BS_ * IN_ * 2;        // 4 MB
    float*          pf  = (float*)w;          w += (size_t)PF_TOT * 4;           // 24 MB
    float*          hsum= (float*)w;          w += (size_t)32 * IN_ * 4;         // 1 MB
    float*          p1  = pf;                 // alias: pf free after k_epi1s (16MB used)
    float*          h1  = (float*)w;          w += (size_t)32 * H_ * 4;
    float*          p2  = (float*)w;          w += (size_t)32 * 32 * H_ * 4;     // 4 MB
    float*          h2  = (float*)w;          w += (size_t)32 * H_ * 4;
    float*          p3  = (float*)w;          w += (size_t)32 * 32 * OUT_ * 4;   // 1 MB
    unsigned short* Yhi = Xhi;                // alias: X dead after gemm1
    unsigned short* Ylo = Xlo;

    k_pre<<<3592, 256, 0, stream>>>(L0, L1, L2, Lb, xs0, xs1, xs2, Xhi, Xlo,
                                    Wc0, Wc1, Wc2, PM);

    k_gemm<<<192, 512, 0, stream>>>(Xhi, Xlo, Lb, pf);
    k_epi0<<<2048, 256, 0, stream>>>(pf, PM + 0 * IN_, PM + 1 * IN_, Yhi, Ylo);
    k_gemm<<<192, 512, 0, stream>>>(Yhi, Ylo, Lb, pf);
    k_epi1s<<<256, 256, 0, stream>>>(pf, PM + 2 * IN_, PM + 3 * IN_, hsum);

    {   // [32,8192]@[8192,1024]: grid (4 h-tiles, 128 k-chunks of 64)
        dim3 g(4, 128);
        k_mlp3<64><<<g, 256, 0, stream>>>(hsum, W_in, p1, IN_, H_);
        k_reduce4<<<32, 256, 0, stream>>>(p1, b_in, h1, 128, 8192, H_, 1);
    }
    {   // [32,1024]@[1024,1024]: grid (4, 32 chunks of 32)
        dim3 g(4, 32);
        k_mlp3<32><<<g, 256, 0, stream>>>(h1, W_h, p2, H_, H_);
        k_reduce4<<<32, 256, 0, stream>>>(p2, b_h, h2, 32, 8192, H_, 1);
    }
    {   // [32,1024]@[1024,256]: grid (1, 32 chunks of 32)
        dim3 g(1, 32);
        k_mlp3<32><<<g, 256, 0, stream>>>(h2, W_out, p3, H_, OUT_);
        k_reduce4<<<8, 256, 0, stream>>>(p3, b_out, (float*)d_out, 32, 2048, OUT_, 0);
    }
}